// Round 6
// baseline (1204.011 us; speedup 1.0000x reference)
//
#include <hip/hip_runtime.h>
#include <hip/hip_bf16.h>

#define NN 2048

typedef unsigned int u32;
typedef unsigned short u16;
typedef unsigned char u8;

__device__ __forceinline__ float bflo(u32 u){ return __uint_as_float(u << 16); }
__device__ __forceinline__ float bfhi(u32 u){ return __uint_as_float(u & 0xffff0000u); }
__device__ __forceinline__ float bf1(u16 u){ return __uint_as_float(((u32)u) << 16); }
__device__ __forceinline__ u16 f2bf(float f){
  __hip_bfloat16 h = __float2bfloat16(f);
  return *reinterpret_cast<u16*>(&h);
}

// Collapse attn_mask (B,R,N,N) int32 + key_padding (B,N) int32 into a combo byte
// per (b,n,m): bit r = attn_mask[b][r][n][m], bit 3 = key_padding[b][m].
__global__ __launch_bounds__(256)
void prep_k(const int* __restrict__ am, const int* __restrict__ kp,
            u8* __restrict__ cmb)
{
  const size_t tid  = (size_t)blockIdx.x * 256 + threadIdx.x;
  const size_t base = tid * 4;
  const int row = (int)(base >> 11);            // b*2048 + n
  const int m0  = (int)(base & 2047);
  const int b = row >> 11, n = row & 2047;
  const size_t e0 = (((size_t)(b*3) * NN) + n) * NN + m0;
  const int4 a0 = *reinterpret_cast<const int4*>(am + e0);
  const int4 a1 = *reinterpret_cast<const int4*>(am + e0 + (size_t)NN*NN);
  const int4 a2 = *reinterpret_cast<const int4*>(am + e0 + 2*(size_t)NN*NN);
  const int4 kv = *reinterpret_cast<const int4*>(kp + (size_t)b*NN + m0);
  const int a0v[4] = {a0.x,a0.y,a0.z,a0.w};
  const int a1v[4] = {a1.x,a1.y,a1.z,a1.w};
  const int a2v[4] = {a2.x,a2.y,a2.z,a2.w};
  const int kvv[4] = {kv.x,kv.y,kv.z,kv.w};
  uchar4 out;
  u8* o = (u8*)&out;
  #pragma unroll
  for (int i = 0; i < 4; ++i)
    o[i] = (u8)((a0v[i]?1:0) | (a1v[i]?2:0) | (a2v[i]?4:0) | (kvv[i]?8:0));
  *reinterpret_cast<uchar4*>(cmb + base) = out;
}

// C[M=4096,512] = A @ W(f32) + bias(f32), f32 accumulate.
// ABF16: A is bf16, else f32. SCATTER: bf16 out to [b*8+h][n][c]. else: OUTF32
// selects f32 vs bf16 row-major out.
template<bool SCATTER, bool ABF16, bool OUTF32>
__global__ __launch_bounds__(256)
void gemm_bias_k(const void* __restrict__ Av, const float* __restrict__ W,
                 const float* __restrict__ bias, void* __restrict__ Cd)
{
  __shared__ float As[32][68];
  __shared__ float Bs[32][68];
  const int t = threadIdx.x;
  const int m0 = blockIdx.x * 64;
  const int n0 = blockIdx.y * 64;
  const int tm = (t >> 4) * 4;
  const int tn = (t & 15) * 4;
  float acc[4][4] = {};

  for (int k0 = 0; k0 < 512; k0 += 32) {
    { // A tile 64x32 -> As[k][m]
      const int row = t >> 2, kk = (t & 3) * 8;
      float f[8];
      if constexpr (ABF16) {
        const u16* A = (const u16*)Av;
        uint4 av = *reinterpret_cast<const uint4*>(A + (size_t)(m0 + row) * 512 + k0 + kk);
        f[0]=bflo(av.x); f[1]=bfhi(av.x); f[2]=bflo(av.y); f[3]=bfhi(av.y);
        f[4]=bflo(av.z); f[5]=bfhi(av.z); f[6]=bflo(av.w); f[7]=bfhi(av.w);
      } else {
        const float* A = (const float*)Av;
        const float4 a0 = *reinterpret_cast<const float4*>(A + (size_t)(m0 + row) * 512 + k0 + kk);
        const float4 a1 = *reinterpret_cast<const float4*>(A + (size_t)(m0 + row) * 512 + k0 + kk + 4);
        f[0]=a0.x; f[1]=a0.y; f[2]=a0.z; f[3]=a0.w;
        f[4]=a1.x; f[5]=a1.y; f[6]=a1.z; f[7]=a1.w;
      }
      #pragma unroll
      for (int i=0;i<8;++i) As[kk+i][row] = f[i];
    }
    { // B tile 32x64 -> Bs[k][n]
      const int row = t >> 3, cc = (t & 7) * 8;
      const float4 b0 = *reinterpret_cast<const float4*>(W + (size_t)(k0 + row) * 512 + n0 + cc);
      const float4 b1 = *reinterpret_cast<const float4*>(W + (size_t)(k0 + row) * 512 + n0 + cc + 4);
      *reinterpret_cast<float4*>(&Bs[row][cc])   = b0;
      *reinterpret_cast<float4*>(&Bs[row][cc+4]) = b1;
    }
    __syncthreads();
    #pragma unroll
    for (int k=0;k<32;++k){
      const float4 a4 = *reinterpret_cast<const float4*>(&As[k][tm]);
      const float4 b4 = *reinterpret_cast<const float4*>(&Bs[k][tn]);
      const float av[4] = {a4.x,a4.y,a4.z,a4.w};
      const float bw[4] = {b4.x,b4.y,b4.z,b4.w};
      #pragma unroll
      for (int i=0;i<4;++i)
        #pragma unroll
        for (int j=0;j<4;++j) acc[i][j] = fmaf(av[i], bw[j], acc[i][j]);
    }
    __syncthreads();
  }

  float bias4[4];
  #pragma unroll
  for (int j=0;j<4;++j) bias4[j] = bias[n0 + tn + j];
  #pragma unroll
  for (int i=0;i<4;++i){
    const int row = m0 + tm + i;
    float v[4];
    #pragma unroll
    for (int j=0;j<4;++j) v[j] = acc[i][j] + bias4[j];
    if constexpr (SCATTER){
      const int b = row & 1, n = row >> 1;
      const int h = (n0 + tn) >> 6, c = (n0 + tn) & 63;
      u16* dst = (u16*)Cd + (((size_t)(b*8 + h) * NN + n) * 64 + c);
      *reinterpret_cast<ushort4*>(dst) =
        make_ushort4(f2bf(v[0]), f2bf(v[1]), f2bf(v[2]), f2bf(v[3]));
    } else if constexpr (OUTF32) {
      float* dst = (float*)Cd + (size_t)row * 512 + n0 + tn;
      *reinterpret_cast<float4*>(dst) = make_float4(v[0], v[1], v[2], v[3]);
    } else {
      u16* dst = (u16*)Cd + (size_t)row * 512 + n0 + tn;
      *reinterpret_cast<ushort4*>(dst) =
        make_ushort4(f2bf(v[0]), f2bf(v[1]), f2bf(v[2]), f2bf(v[3]));
    }
  }
}

// Flash attention with relative-bias from combo bytes. Q/K/V: [b*8+h][n][64] bf16.
__global__ __launch_bounds__(256)
void attn_k(const u16* __restrict__ Q, const u16* __restrict__ K,
            const u16* __restrict__ V, const u8* __restrict__ cmb,
            const float* __restrict__ mw, u16* __restrict__ O)
{
  __shared__ u16 Ks[64*64];   // [m][c], c-slot XORed by (m&7)
  __shared__ u16 Vs[64*64];   // transposed [c][m], m-slot XORed by (c&7)
  __shared__ float qs[16*64];
  __shared__ u16 Ps[16*64];

  const int t = threadIdx.x;
  const int lane = t & 63;
  const int w = t >> 6;
  const int bh = blockIdx.y;
  const int b = bh >> 3, h = bh & 7;
  const int n0 = blockIdx.x * 16;
  const float NEGINF = -__builtin_inff();

  const float mw0 = mw[h*4+0], mw1 = mw[h*4+1], mw2 = mw[h*4+2];
  const float msc = mw[h*4+3];
  const float mxw = fmaxf(mw0, fmaxf(mw1, mw2));
  const float e0 = __expf(mw0-mxw), e1 = __expf(mw1-mxw), e2 = __expf(mw2-mxw);
  const float inv = msc / (e0+e1+e2);
  const float rw0 = e0*inv, rw1 = e1*inv, rw2 = e2*inv;

  { // stage q, scaled by 1/sqrt(64)
    const int row = t >> 4, c0 = (t & 15) * 4;
    const uint2 qv = *reinterpret_cast<const uint2*>(Q + ((size_t)bh*NN + n0 + row)*64 + c0);
    float4 f = make_float4(bflo(qv.x)*0.125f, bfhi(qv.x)*0.125f,
                           bflo(qv.y)*0.125f, bfhi(qv.y)*0.125f);
    *reinterpret_cast<float4*>(&qs[row*64 + c0]) = f;
  }

  float m_run[4], l_run[4], o_acc[4];
  #pragma unroll
  for (int r=0;r<4;++r){ m_run[r] = NEGINF; l_run[r] = 0.f; o_acc[r] = 0.f; }

  const int sm  = t >> 2;
  const int sc0 = (t & 3) * 16;

  for (int mt = 0; mt < 32; ++mt){
    const int m0 = mt * 64;
    __syncthreads();
    { // stage K
      const uint4* src = reinterpret_cast<const uint4*>(K + ((size_t)bh*NN + m0 + sm)*64 + sc0);
      uint4 k0v = src[0], k1v = src[1];
      const int s0 = sc0 >> 3;
      *reinterpret_cast<uint4*>(&Ks[sm*64 + (((s0    ) ^ (sm & 7)) << 3)]) = k0v;
      *reinterpret_cast<uint4*>(&Ks[sm*64 + (((s0 + 1) ^ (sm & 7)) << 3)]) = k1v;
    }
    { // stage V transposed
      const uint4* src = reinterpret_cast<const uint4*>(V + ((size_t)bh*NN + m0 + sm)*64 + sc0);
      uint4 v0v = src[0], v1v = src[1];
      u16 e[16];
      e[0]=v0v.x&0xffff; e[1]=v0v.x>>16; e[2]=v0v.y&0xffff; e[3]=v0v.y>>16;
      e[4]=v0v.z&0xffff; e[5]=v0v.z>>16; e[6]=v0v.w&0xffff; e[7]=v0v.w>>16;
      e[8]=v1v.x&0xffff; e[9]=v1v.x>>16; e[10]=v1v.y&0xffff; e[11]=v1v.y>>16;
      e[12]=v1v.z&0xffff; e[13]=v1v.z>>16; e[14]=v1v.w&0xffff; e[15]=v1v.w>>16;
      #pragma unroll
      for (int i=0;i<16;++i){
        const int c = sc0 + i;
        Vs[c*64 + ((((sm>>3) ^ (c&7)) << 3) | (sm & 7))] = e[i];
      }
    }
    __syncthreads();

    float s_arr[4];
    #pragma unroll
    for (int rr=0; rr<4; ++rr){
      const int n = n0 + (w<<2) + rr;
      const u8 ci = cmb[((size_t)(b*NN + n))*NN + m0 + lane];
      float s = 0.f;
      #pragma unroll
      for (int cc=0; cc<8; ++cc){
        const uint4 k8 = *reinterpret_cast<const uint4*>(&Ks[lane*64 + ((cc ^ (lane&7)) << 3)]);
        const float4 qa = *reinterpret_cast<const float4*>(&qs[((w<<2)+rr)*64 + cc*8]);
        const float4 qb = *reinterpret_cast<const float4*>(&qs[((w<<2)+rr)*64 + cc*8 + 4]);
        s = fmaf(qa.x, bflo(k8.x), s); s = fmaf(qa.y, bfhi(k8.x), s);
        s = fmaf(qa.z, bflo(k8.y), s); s = fmaf(qa.w, bfhi(k8.y), s);
        s = fmaf(qb.x, bflo(k8.z), s); s = fmaf(qb.y, bfhi(k8.z), s);
        s = fmaf(qb.z, bflo(k8.w), s); s = fmaf(qb.w, bfhi(k8.w), s);
      }
      float relv = 0.f;
      relv += (ci & 1) ? 0.f : rw0;
      relv += (ci & 2) ? 0.f : rw1;
      relv += (ci & 4) ? 0.f : rw2;
      s_arr[rr] = (ci & 8) ? NEGINF : (s + relv);
    }

    #pragma unroll
    for (int rr=0; rr<4; ++rr){
      float s = s_arr[rr];
      float tmax = s;
      #pragma unroll
      for (int off=32; off; off>>=1) tmax = fmaxf(tmax, __shfl_xor(tmax, off));
      const float nm = fmaxf(m_run[rr], tmax);
      float p, sc;
      if (nm == NEGINF){ p = 0.f; sc = 1.f; }
      else { sc = __expf(m_run[rr] - nm); p = __expf(s - nm); m_run[rr] = nm; }
      float ps = p;
      #pragma unroll
      for (int off=32; off; off>>=1) ps += __shfl_xor(ps, off);
      l_run[rr] = l_run[rr]*sc + ps;
      o_acc[rr] *= sc;
      Ps[((w<<2)+rr)*64 + lane] = f2bf(p);
    }
    __syncthreads();

    #pragma unroll
    for (int jj=0; jj<8; ++jj){
      const uint4 v8 = *reinterpret_cast<const uint4*>(&Vs[lane*64 + ((jj ^ (lane&7)) << 3)]);
      const float v0=bflo(v8.x), v1=bfhi(v8.x), v2=bflo(v8.y), v3=bfhi(v8.y);
      const float v4=bflo(v8.z), v5=bfhi(v8.z), v6=bflo(v8.w), v7=bfhi(v8.w);
      #pragma unroll
      for (int rr=0; rr<4; ++rr){
        const uint4 p8 = *reinterpret_cast<const uint4*>(&Ps[((w<<2)+rr)*64 + jj*8]);
        float o = o_acc[rr];
        o = fmaf(bflo(p8.x), v0, o); o = fmaf(bfhi(p8.x), v1, o);
        o = fmaf(bflo(p8.y), v2, o); o = fmaf(bfhi(p8.y), v3, o);
        o = fmaf(bflo(p8.z), v4, o); o = fmaf(bfhi(p8.z), v5, o);
        o = fmaf(bflo(p8.w), v6, o); o = fmaf(bfhi(p8.w), v7, o);
        o_acc[rr] = o;
      }
    }
  }

  #pragma unroll
  for (int rr=0; rr<4; ++rr){
    const int n = n0 + (w<<2) + rr;
    const float res = o_acc[rr] / l_run[rr];
    O[((size_t)(n*2 + b))*512 + h*64 + lane] = f2bf(res);
  }
}

extern "C" void kernel_launch(void* const* d_in, const int* in_sizes, int n_in,
                              void* d_out, int out_size, void* d_ws, size_t ws_size,
                              hipStream_t stream)
{
  const float* xq = (const float*)d_in[0];
  const float* xk = (const float*)d_in[1];
  const float* xv = (const float*)d_in[2];
  const int*   am = (const int*)d_in[3];
  const int*   kp = (const int*)d_in[4];
  const float* Wq = (const float*)d_in[5];
  const float* bq = (const float*)d_in[6];
  const float* Wk = (const float*)d_in[7];
  const float* bk = (const float*)d_in[8];
  const float* Wv = (const float*)d_in[9];
  const float* bv = (const float*)d_in[10];
  const float* Wo = (const float*)d_in[11];
  const float* bo = (const float*)d_in[12];
  const float* mw = (const float*)d_in[13];

  u16* Qb = (u16*)d_ws;                       // [16][2048][64] bf16, 4 MB
  u16* Kb = Qb + (size_t)16*NN*64;
  u16* Vb = Kb + (size_t)16*NN*64;
  u16* Ob = Vb + (size_t)16*NN*64;            // [4096][512] bf16, 4 MB
  u8*  cmb = (u8*)(Ob + (size_t)4096*512);    // [2][2048][2048] bytes, 8 MB

  prep_k<<<(2*NN*NN/4 + 255)/256, 256, 0, stream>>>(am, kp, cmb);

  dim3 gg(64, 8);
  gemm_bias_k<true , false, false><<<gg, 256, 0, stream>>>(xq, Wq, bq, Qb);
  gemm_bias_k<true , false, false><<<gg, 256, 0, stream>>>(xk, Wk, bk, Kb);
  gemm_bias_k<true , false, false><<<gg, 256, 0, stream>>>(xv, Wv, bv, Vb);
  attn_k<<<dim3(128, 16), 256, 0, stream>>>(Qb, Kb, Vb, cmb, mw, Ob);
  gemm_bias_k<false, true , true ><<<gg, 256, 0, stream>>>(Ob, Wo, bo, d_out);
}

// Round 7
// 245.666 us; speedup vs baseline: 4.9010x; 4.9010x over previous
//
#include <hip/hip_runtime.h>
#include <hip/hip_bf16.h>

#define NN 2048

typedef unsigned int u32;
typedef unsigned short u16;
typedef unsigned char u8;

typedef __attribute__((ext_vector_type(8))) short short8;
typedef __attribute__((ext_vector_type(4))) float f32x4;

__device__ __forceinline__ float bflo(u32 u){ return __uint_as_float(u << 16); }
__device__ __forceinline__ float bfhi(u32 u){ return __uint_as_float(u & 0xffff0000u); }
__device__ __forceinline__ u16 f2bf(float f){
  __hip_bfloat16 h = __float2bfloat16(f);
  return *reinterpret_cast<u16*>(&h);
}

// Collapse attn_mask (B,R,N,N) int32 + key_padding (B,N) int32 into a combo byte
// per (b,n,m): bit r = attn_mask[b][r][n][m], bit 3 = key_padding[b][m].
__global__ __launch_bounds__(256)
void prep_k(const int* __restrict__ am, const int* __restrict__ kp,
            u8* __restrict__ cmb)
{
  const size_t tid  = (size_t)blockIdx.x * 256 + threadIdx.x;
  const size_t base = tid * 4;
  const int row = (int)(base >> 11);            // b*2048 + n
  const int m0  = (int)(base & 2047);
  const int b = row >> 11, n = row & 2047;
  const size_t e0 = (((size_t)(b*3) * NN) + n) * NN + m0;
  const int4 a0 = *reinterpret_cast<const int4*>(am + e0);
  const int4 a1 = *reinterpret_cast<const int4*>(am + e0 + (size_t)NN*NN);
  const int4 a2 = *reinterpret_cast<const int4*>(am + e0 + 2*(size_t)NN*NN);
  const int4 kv = *reinterpret_cast<const int4*>(kp + (size_t)b*NN + m0);
  const int a0v[4] = {a0.x,a0.y,a0.z,a0.w};
  const int a1v[4] = {a1.x,a1.y,a1.z,a1.w};
  const int a2v[4] = {a2.x,a2.y,a2.z,a2.w};
  const int kvv[4] = {kv.x,kv.y,kv.z,kv.w};
  uchar4 out;
  u8* o = (u8*)&out;
  #pragma unroll
  for (int i = 0; i < 4; ++i)
    o[i] = (u8)((a0v[i]?1:0) | (a1v[i]?2:0) | (a2v[i]?4:0) | (kvv[i]?8:0));
  *reinterpret_cast<uchar4*>(cmb + base) = out;
}

// C[M=4096,512] = A @ W(f32) + bias(f32), f32 accumulate.
template<bool SCATTER, bool ABF16, bool OUTF32>
__global__ __launch_bounds__(256)
void gemm_bias_k(const void* __restrict__ Av, const float* __restrict__ W,
                 const float* __restrict__ bias, void* __restrict__ Cd)
{
  __shared__ float As[32][68];
  __shared__ float Bs[32][68];
  const int t = threadIdx.x;
  const int m0 = blockIdx.x * 64;
  const int n0 = blockIdx.y * 64;
  const int tm = (t >> 4) * 4;
  const int tn = (t & 15) * 4;
  float acc[4][4] = {};

  for (int k0 = 0; k0 < 512; k0 += 32) {
    {
      const int row = t >> 2, kk = (t & 3) * 8;
      float f[8];
      if constexpr (ABF16) {
        const u16* A = (const u16*)Av;
        uint4 av = *reinterpret_cast<const uint4*>(A + (size_t)(m0 + row) * 512 + k0 + kk);
        f[0]=bflo(av.x); f[1]=bfhi(av.x); f[2]=bflo(av.y); f[3]=bfhi(av.y);
        f[4]=bflo(av.z); f[5]=bfhi(av.z); f[6]=bflo(av.w); f[7]=bfhi(av.w);
      } else {
        const float* A = (const float*)Av;
        const float4 a0 = *reinterpret_cast<const float4*>(A + (size_t)(m0 + row) * 512 + k0 + kk);
        const float4 a1 = *reinterpret_cast<const float4*>(A + (size_t)(m0 + row) * 512 + k0 + kk + 4);
        f[0]=a0.x; f[1]=a0.y; f[2]=a0.z; f[3]=a0.w;
        f[4]=a1.x; f[5]=a1.y; f[6]=a1.z; f[7]=a1.w;
      }
      #pragma unroll
      for (int i=0;i<8;++i) As[kk+i][row] = f[i];
    }
    {
      const int row = t >> 3, cc = (t & 7) * 8;
      const float4 b0 = *reinterpret_cast<const float4*>(W + (size_t)(k0 + row) * 512 + n0 + cc);
      const float4 b1 = *reinterpret_cast<const float4*>(W + (size_t)(k0 + row) * 512 + n0 + cc + 4);
      *reinterpret_cast<float4*>(&Bs[row][cc])   = b0;
      *reinterpret_cast<float4*>(&Bs[row][cc+4]) = b1;
    }
    __syncthreads();
    #pragma unroll
    for (int k=0;k<32;++k){
      const float4 a4 = *reinterpret_cast<const float4*>(&As[k][tm]);
      const float4 b4 = *reinterpret_cast<const float4*>(&Bs[k][tn]);
      const float av[4] = {a4.x,a4.y,a4.z,a4.w};
      const float bw[4] = {b4.x,b4.y,b4.z,b4.w};
      #pragma unroll
      for (int i=0;i<4;++i)
        #pragma unroll
        for (int j=0;j<4;++j) acc[i][j] = fmaf(av[i], bw[j], acc[i][j]);
    }
    __syncthreads();
  }

  float bias4[4];
  #pragma unroll
  for (int j=0;j<4;++j) bias4[j] = bias[n0 + tn + j];
  #pragma unroll
  for (int i=0;i<4;++i){
    const int row = m0 + tm + i;
    float v[4];
    #pragma unroll
    for (int j=0;j<4;++j) v[j] = acc[i][j] + bias4[j];
    if constexpr (SCATTER){
      const int b = row & 1, n = row >> 1;
      const int h = (n0 + tn) >> 6, c = (n0 + tn) & 63;
      u16* dst = (u16*)Cd + (((size_t)(b*8 + h) * NN + n) * 64 + c);
      *reinterpret_cast<ushort4*>(dst) =
        make_ushort4(f2bf(v[0]), f2bf(v[1]), f2bf(v[2]), f2bf(v[3]));
    } else if constexpr (OUTF32) {
      float* dst = (float*)Cd + (size_t)row * 512 + n0 + tn;
      *reinterpret_cast<float4*>(dst) = make_float4(v[0], v[1], v[2], v[3]);
    } else {
      u16* dst = (u16*)Cd + (size_t)row * 512 + n0 + tn;
      *reinterpret_cast<ushort4*>(dst) =
        make_ushort4(f2bf(v[0]), f2bf(v[1]), f2bf(v[2]), f2bf(v[3]));
    }
  }
}

// MFMA flash attention. Q/K/V: [b*8+h][n][64] bf16. Block = 4 waves, 64 queries.
// Wave w owns queries n0+w*16+q (q=lane&15). Swapped QK^T: S^T = mfma(K, Q) so
// softmax reduction over keys is lane-local (16 vals) + 2 shuffles.
__global__ __launch_bounds__(256)
void attn_mfma(const u16* __restrict__ Q, const u16* __restrict__ K,
               const u16* __restrict__ V, const u8* __restrict__ cmb,
               const float* __restrict__ mw, u16* __restrict__ O)
{
  __shared__ u16 Ks[64*64];    // [key][ch], ch-slot(8) XOR (key&7)
  __shared__ u16 Vs[64*64];    // [ch][key], key-slot(8) XOR (ch&7)
  __shared__ u16 Ps[4][16*64]; // per wave: [q][key], key-slot(8) XOR (q&7)

  const int t = threadIdx.x;
  const int lane = t & 63;
  const int w = t >> 6;
  const int g = lane >> 4;       // 0..3
  const int r15 = lane & 15;     // MFMA row/col lane index
  const int bh = blockIdx.y;
  const int b = bh >> 3, h = bh & 7;
  const int n0 = blockIdx.x * 64;
  const int nq = n0 + w*16 + r15;    // this lane's query (as MFMA col)
  const float NEGINF = -__builtin_inff();

  // per-head rel-bias weights: softmax(mw[h,0:3]) * mw[h,3]
  const float mw0 = mw[h*4+0], mw1 = mw[h*4+1], mw2 = mw[h*4+2];
  const float msc = mw[h*4+3];
  const float mxw = fmaxf(mw0, fmaxf(mw1, mw2));
  const float e0 = __expf(mw0-mxw), e1 = __expf(mw1-mxw), e2 = __expf(mw2-mxw);
  const float inv = msc / (e0+e1+e2);
  const float rw0 = e0*inv, rw1 = e1*inv, rw2 = e2*inv;

  // Q B-fragments, loaded once: B[k=8g+i][col=q] = Q[nq][ch]
  const u16* qrow = Q + ((size_t)bh*NN + nq)*64;
  const short8 bq0 = *reinterpret_cast<const short8*>(qrow + 8*g);
  const short8 bq1 = *reinterpret_cast<const short8*>(qrow + 32 + 8*g);

  const u8* crow = cmb + ((size_t)(b*NN + nq))*NN;

  float m_run = NEGINF, l_run = 0.f;
  const f32x4 fz = {0.f, 0.f, 0.f, 0.f};
  f32x4 oacc[4] = {fz, fz, fz, fz};   // O^T channel tiles

  const int sm  = t >> 2;        // staging key row 0..63
  const int sc0 = (t & 3) * 16;  // staging ch base

  for (int it = 0; it < 32; ++it) {
    const int m0 = it * 64;
    __syncthreads();
    { // stage K row-major, slot-swizzled
      const uint4* src = reinterpret_cast<const uint4*>(K + ((size_t)bh*NN + m0 + sm)*64 + sc0);
      uint4 k0v = src[0], k1v = src[1];
      const int s0 = sc0 >> 3;
      *reinterpret_cast<uint4*>(&Ks[sm*64 + (((s0    ) ^ (sm & 7)) << 3)]) = k0v;
      *reinterpret_cast<uint4*>(&Ks[sm*64 + (((s0 + 1) ^ (sm & 7)) << 3)]) = k1v;
    }
    { // stage V transposed, slot-swizzled
      const uint4* src = reinterpret_cast<const uint4*>(V + ((size_t)bh*NN + m0 + sm)*64 + sc0);
      uint4 v0v = src[0], v1v = src[1];
      u16 e[16];
      e[0]=v0v.x&0xffff; e[1]=v0v.x>>16; e[2]=v0v.y&0xffff; e[3]=v0v.y>>16;
      e[4]=v0v.z&0xffff; e[5]=v0v.z>>16; e[6]=v0v.w&0xffff; e[7]=v0v.w>>16;
      e[8]=v1v.x&0xffff; e[9]=v1v.x>>16; e[10]=v1v.y&0xffff; e[11]=v1v.y>>16;
      e[12]=v1v.z&0xffff; e[13]=v1v.z>>16; e[14]=v1v.w&0xffff; e[15]=v1v.w>>16;
      #pragma unroll
      for (int i=0;i<16;++i){
        const int c = sc0 + i;
        Vs[c*64 + ((((sm>>3) ^ (c&7)) << 3) | (sm & 7))] = e[i];
      }
    }
    __syncthreads();

    // S^T = K @ Q^T : 4 key tiles x (K=64ch -> 2 mfma)
    f32x4 sac[4];
    #pragma unroll
    for (int kt = 0; kt < 4; ++kt) {
      const int key = 16*kt + r15;   // A-frag row
      const short8 a0 = *reinterpret_cast<const short8*>(&Ks[key*64 + (((g  ) ^ (key&7)) << 3)]);
      const short8 a1 = *reinterpret_cast<const short8*>(&Ks[key*64 + (((g+4) ^ (key&7)) << 3)]);
      f32x4 s = fz;
      s = __builtin_amdgcn_mfma_f32_16x16x32_bf16(a0, bq0, s, 0, 0, 0);
      s = __builtin_amdgcn_mfma_f32_16x16x32_bf16(a1, bq1, s, 0, 0, 0);
      sac[kt] = s;
    }

    // rel bias + mask + lane-local max
    float sv[4][4];
    float pmax = NEGINF;
    #pragma unroll
    for (int kt = 0; kt < 4; ++kt) {
      const u32 cw = *reinterpret_cast<const u32*>(crow + m0 + 16*kt + 4*g);
      #pragma unroll
      for (int j = 0; j < 4; ++j) {
        const u32 ci = (cw >> (8*j)) & 0xffu;
        float x = sac[kt][j] * 0.125f;
        x += (ci & 1) ? 0.f : rw0;
        x += (ci & 2) ? 0.f : rw1;
        x += (ci & 4) ? 0.f : rw2;
        sv[kt][j] = (ci & 8) ? NEGINF : x;
        pmax = fmaxf(pmax, sv[kt][j]);
      }
    }
    float tmax = pmax;
    tmax = fmaxf(tmax, __shfl_xor(tmax, 16));
    tmax = fmaxf(tmax, __shfl_xor(tmax, 32));

    const float nm = fmaxf(m_run, tmax);
    float sc;
    if (nm == NEGINF) { sc = 1.f; }
    else { sc = __expf(m_run - nm); m_run = nm; }

    // P = exp(S - m), write P^T (bf16) to per-wave Ps
    float psum = 0.f;
    #pragma unroll
    for (int kt = 0; kt < 4; ++kt) {
      float p[4];
      #pragma unroll
      for (int j = 0; j < 4; ++j) {
        p[j] = (nm == NEGINF) ? 0.f : __expf(sv[kt][j] - nm);
        psum += p[j];
      }
      const int slot = 2*kt + (g >> 1);
      const int off  = 4 * (g & 1);
      *reinterpret_cast<ushort4*>(&Ps[w][r15*64 + ((slot ^ (r15 & 7)) << 3) + off]) =
        make_ushort4(f2bf(p[0]), f2bf(p[1]), f2bf(p[2]), f2bf(p[3]));
    }
    psum += __shfl_xor(psum, 16);
    psum += __shfl_xor(psum, 32);
    l_run = l_run * sc + psum;
    #pragma unroll
    for (int ct = 0; ct < 4; ++ct) oacc[ct] *= sc;

    __syncthreads();   // Ps visibility across lanes

    // O^T += V^T @ P^T : 4 channel tiles x 2 mfma
    const short8 bp0 = *reinterpret_cast<const short8*>(&Ps[w][r15*64 + (((g  ) ^ (r15 & 7)) << 3)]);
    const short8 bp1 = *reinterpret_cast<const short8*>(&Ps[w][r15*64 + (((g+4) ^ (r15 & 7)) << 3)]);
    #pragma unroll
    for (int ct = 0; ct < 4; ++ct) {
      const int c = 16*ct + r15;   // A-frag row = channel
      const short8 av0 = *reinterpret_cast<const short8*>(&Vs[c*64 + (((g  ) ^ (c&7)) << 3)]);
      const short8 av1 = *reinterpret_cast<const short8*>(&Vs[c*64 + (((g+4) ^ (c&7)) << 3)]);
      oacc[ct] = __builtin_amdgcn_mfma_f32_16x16x32_bf16(av0, bp0, oacc[ct], 0, 0, 0);
      oacc[ct] = __builtin_amdgcn_mfma_f32_16x16x32_bf16(av1, bp1, oacc[ct], 0, 0, 0);
    }
  }

  // epilogue: O[nq][c] = O^T[c][nq] / l_run  (C-frag: row c = 16ct+4g+j, col q=r15)
  const float rinv = 1.f / l_run;
  #pragma unroll
  for (int ct = 0; ct < 4; ++ct) {
    u16* dst = O + ((size_t)(nq*2 + b))*512 + h*64 + 16*ct + 4*g;
    *reinterpret_cast<ushort4*>(dst) =
      make_ushort4(f2bf(oacc[ct][0]*rinv), f2bf(oacc[ct][1]*rinv),
                   f2bf(oacc[ct][2]*rinv), f2bf(oacc[ct][3]*rinv));
  }
}

extern "C" void kernel_launch(void* const* d_in, const int* in_sizes, int n_in,
                              void* d_out, int out_size, void* d_ws, size_t ws_size,
                              hipStream_t stream)
{
  const float* xq = (const float*)d_in[0];
  const float* xk = (const float*)d_in[1];
  const float* xv = (const float*)d_in[2];
  const int*   am = (const int*)d_in[3];
  const int*   kp = (const int*)d_in[4];
  const float* Wq = (const float*)d_in[5];
  const float* bq = (const float*)d_in[6];
  const float* Wk = (const float*)d_in[7];
  const float* bk = (const float*)d_in[8];
  const float* Wv = (const float*)d_in[9];
  const float* bv = (const float*)d_in[10];
  const float* Wo = (const float*)d_in[11];
  const float* bo = (const float*)d_in[12];
  const float* mw = (const float*)d_in[13];

  u16* Qb = (u16*)d_ws;                       // [16][2048][64] bf16, 4 MB
  u16* Kb = Qb + (size_t)16*NN*64;
  u16* Vb = Kb + (size_t)16*NN*64;
  u16* Ob = Vb + (size_t)16*NN*64;            // [4096][512] bf16, 4 MB
  u8*  cmb = (u8*)(Ob + (size_t)4096*512);    // [2][2048][2048] bytes, 8 MB

  prep_k<<<(2*NN*NN/4 + 255)/256, 256, 0, stream>>>(am, kp, cmb);

  dim3 gg(64, 8);
  gemm_bias_k<true , false, false><<<gg, 256, 0, stream>>>(xq, Wq, bq, Qb);
  gemm_bias_k<true , false, false><<<gg, 256, 0, stream>>>(xk, Wk, bk, Kb);
  gemm_bias_k<true , false, false><<<gg, 256, 0, stream>>>(xv, Wv, bv, Vb);
  attn_mfma<<<dim3(32, 16), 256, 0, stream>>>(Qb, Kb, Vb, cmb, mw, Ob);
  gemm_bias_k<false, true , true ><<<gg, 256, 0, stream>>>(Ob, Wo, bo, d_out);
}

// Round 8
// 173.664 us; speedup vs baseline: 6.9330x; 1.4146x over previous
//
#include <hip/hip_runtime.h>
#include <hip/hip_bf16.h>

#define NN 2048

typedef unsigned int u32;
typedef unsigned short u16;
typedef unsigned char u8;

typedef __attribute__((ext_vector_type(8))) short short8;
typedef __attribute__((ext_vector_type(4))) float f32x4;

__device__ __forceinline__ float bflo(u32 u){ return __uint_as_float(u << 16); }
__device__ __forceinline__ float bfhi(u32 u){ return __uint_as_float(u & 0xffff0000u); }
__device__ __forceinline__ u16 f2bf(float f){
  __hip_bfloat16 h = __float2bfloat16(f);
  return *reinterpret_cast<u16*>(&h);
}

// Collapse attn_mask (B,R,N,N) int32 + key_padding (B,N) int32 into a combo byte
// per (b,n,m): bit r = attn_mask[b][r][n][m], bit 3 = key_padding[b][m].
__global__ __launch_bounds__(256)
void prep_k(const int* __restrict__ am, const int* __restrict__ kp,
            u8* __restrict__ cmb)
{
  const size_t tid  = (size_t)blockIdx.x * 256 + threadIdx.x;
  const size_t base = tid * 4;
  const int row = (int)(base >> 11);            // b*2048 + n
  const int m0  = (int)(base & 2047);
  const int b = row >> 11, n = row & 2047;
  const size_t e0 = (((size_t)(b*3) * NN) + n) * NN + m0;
  const int4 a0 = *reinterpret_cast<const int4*>(am + e0);
  const int4 a1 = *reinterpret_cast<const int4*>(am + e0 + (size_t)NN*NN);
  const int4 a2 = *reinterpret_cast<const int4*>(am + e0 + 2*(size_t)NN*NN);
  const int4 kv = *reinterpret_cast<const int4*>(kp + (size_t)b*NN + m0);
  const int a0v[4] = {a0.x,a0.y,a0.z,a0.w};
  const int a1v[4] = {a1.x,a1.y,a1.z,a1.w};
  const int a2v[4] = {a2.x,a2.y,a2.z,a2.w};
  const int kvv[4] = {kv.x,kv.y,kv.z,kv.w};
  uchar4 out;
  u8* o = (u8*)&out;
  #pragma unroll
  for (int i = 0; i < 4; ++i)
    o[i] = (u8)((a0v[i]?1:0) | (a1v[i]?2:0) | (a2v[i]?4:0) | (kvv[i]?8:0));
  *reinterpret_cast<uchar4*>(cmb + base) = out;
}

// MFMA GEMM: C[4096,512] = A @ W + bias. BM=64 BN=128 BK=64, 4 waves.
// Wave w owns cols wn..wn+31 (2 frag-cols), all 64 rows (4 frag-rows).
// As[m][k] and Ws[n][k] both bf16 with 8-elem slot XOR-swizzle (slot ^ (row&7)).
template<bool SCATTER, bool ABF16, bool OUTF32>
__global__ __launch_bounds__(256)
void gemm_mfma(const void* __restrict__ Av, const float* __restrict__ W,
               const float* __restrict__ bias, void* __restrict__ Cd)
{
  __shared__ u16 As[64*64];    // [m][k]
  __shared__ u16 Ws[128*64];   // [n][k] (transposed W)

  const int t = threadIdx.x;
  const int lane = t & 63;
  const int w = t >> 6;
  const int g = lane >> 4, r15 = lane & 15;
  const int m0 = blockIdx.x * 64;
  const int n0 = blockIdx.y * 128;
  const int wn = w * 32;

  const f32x4 fz = {0.f,0.f,0.f,0.f};
  f32x4 acc[4][2] = {{fz,fz},{fz,fz},{fz,fz},{fz,fz}};

  for (int k0 = 0; k0 < 512; k0 += 64) {
    { // stage A tile 64 rows x 64 k
      const int row = t >> 2, kc = (t & 3) * 16;
      u32 pk[8];
      if constexpr (ABF16) {
        const u16* A = (const u16*)Av;
        const uint4 v0 = *reinterpret_cast<const uint4*>(A + (size_t)(m0+row)*512 + k0 + kc);
        const uint4 v1 = *reinterpret_cast<const uint4*>(A + (size_t)(m0+row)*512 + k0 + kc + 8);
        pk[0]=v0.x; pk[1]=v0.y; pk[2]=v0.z; pk[3]=v0.w;
        pk[4]=v1.x; pk[5]=v1.y; pk[6]=v1.z; pk[7]=v1.w;
      } else {
        const float* A = (const float*)Av;
        float f[16];
        #pragma unroll
        for (int q = 0; q < 4; ++q) {
          const float4 v = *reinterpret_cast<const float4*>(A + (size_t)(m0+row)*512 + k0 + kc + 4*q);
          f[4*q]=v.x; f[4*q+1]=v.y; f[4*q+2]=v.z; f[4*q+3]=v.w;
        }
        #pragma unroll
        for (int q = 0; q < 8; ++q)
          pk[q] = (u32)f2bf(f[2*q]) | ((u32)f2bf(f[2*q+1]) << 16);
      }
      const int s0 = (t & 3) * 2;
      uint4 w0, w1;
      w0.x=pk[0]; w0.y=pk[1]; w0.z=pk[2]; w0.w=pk[3];
      w1.x=pk[4]; w1.y=pk[5]; w1.z=pk[6]; w1.w=pk[7];
      *reinterpret_cast<uint4*>(&As[row*64 + (((s0  ) ^ (row&7)) << 3)]) = w0;
      *reinterpret_cast<uint4*>(&As[row*64 + (((s0+1) ^ (row&7)) << 3)]) = w1;
    }
    { // stage W tile 64 k-rows x 128 n -> Ws[n][k] transposed
      const int kr = t >> 2;           // 0..63
      const int ncb = (t & 3) * 32;    // n base
      const float* wrow = W + (size_t)(k0 + kr) * 512 + n0 + ncb;
      #pragma unroll
      for (int i = 0; i < 8; ++i) {
        const float4 wv = *reinterpret_cast<const float4*>(wrow + i*4);
        const float fv[4] = {wv.x, wv.y, wv.z, wv.w};
        #pragma unroll
        for (int j2 = 0; j2 < 4; ++j2) {
          const int n = ncb + i*4 + j2;
          Ws[n*64 + ((((kr>>3) ^ (n&7)) << 3) | (kr & 7))] = f2bf(fv[j2]);
        }
      }
    }
    __syncthreads();

    #pragma unroll
    for (int ks = 0; ks < 2; ++ks) {
      short8 bfr[2], afr[4];
      #pragma unroll
      for (int ni = 0; ni < 2; ++ni) {
        const int n = wn + 16*ni + r15;
        bfr[ni] = *reinterpret_cast<const short8*>(&Ws[n*64 + (((ks*4+g) ^ (n&7)) << 3)]);
      }
      #pragma unroll
      for (int mi = 0; mi < 4; ++mi) {
        const int m = 16*mi + r15;
        afr[mi] = *reinterpret_cast<const short8*>(&As[m*64 + (((ks*4+g) ^ (m&7)) << 3)]);
      }
      #pragma unroll
      for (int mi = 0; mi < 4; ++mi)
        #pragma unroll
        for (int ni = 0; ni < 2; ++ni)
          acc[mi][ni] = __builtin_amdgcn_mfma_f32_16x16x32_bf16(afr[mi], bfr[ni], acc[mi][ni], 0, 0, 0);
    }
    __syncthreads();
  }

  const float bia[2] = { bias[n0 + wn + r15], bias[n0 + wn + 16 + r15] };
  #pragma unroll
  for (int mi = 0; mi < 4; ++mi) {
    #pragma unroll
    for (int ni = 0; ni < 2; ++ni) {
      #pragma unroll
      for (int j = 0; j < 4; ++j) {
        const int row = m0 + 16*mi + 4*g + j;
        const int col = n0 + wn + 16*ni + r15;
        const float v = acc[mi][ni][j] + bia[ni];
        if constexpr (SCATTER) {
          const int bb = row & 1, ntok = row >> 1;
          const int h = col >> 6, c = col & 63;
          ((u16*)Cd)[(((size_t)(bb*8 + h) * NN + ntok) * 64) + c] = f2bf(v);
        } else if constexpr (OUTF32) {
          ((float*)Cd)[(size_t)row * 512 + col] = v;
        } else {
          ((u16*)Cd)[(size_t)row * 512 + col] = f2bf(v);
        }
      }
    }
  }
}

// MFMA flash attention (verified round 7). Q/K/V: [b*8+h][n][64] bf16.
__global__ __launch_bounds__(256)
void attn_mfma(const u16* __restrict__ Q, const u16* __restrict__ K,
               const u16* __restrict__ V, const u8* __restrict__ cmb,
               const float* __restrict__ mw, u16* __restrict__ O)
{
  __shared__ u16 Ks[64*64];    // [key][ch], ch-slot(8) XOR (key&7)
  __shared__ u16 Vs[64*64];    // [ch][key], key-slot(8) XOR (ch&7)
  __shared__ u16 Ps[4][16*64]; // per wave: [q][key], key-slot(8) XOR (q&7)

  const int t = threadIdx.x;
  const int lane = t & 63;
  const int w = t >> 6;
  const int g = lane >> 4;
  const int r15 = lane & 15;
  const int bh = blockIdx.y;
  const int b = bh >> 3, h = bh & 7;
  const int n0 = blockIdx.x * 64;
  const int nq = n0 + w*16 + r15;
  const float NEGINF = -__builtin_inff();

  const float mw0 = mw[h*4+0], mw1 = mw[h*4+1], mw2 = mw[h*4+2];
  const float msc = mw[h*4+3];
  const float mxw = fmaxf(mw0, fmaxf(mw1, mw2));
  const float e0 = __expf(mw0-mxw), e1 = __expf(mw1-mxw), e2 = __expf(mw2-mxw);
  const float inv = msc / (e0+e1+e2);
  const float rw0 = e0*inv, rw1 = e1*inv, rw2 = e2*inv;

  const u16* qrow = Q + ((size_t)bh*NN + nq)*64;
  const short8 bq0 = *reinterpret_cast<const short8*>(qrow + 8*g);
  const short8 bq1 = *reinterpret_cast<const short8*>(qrow + 32 + 8*g);

  const u8* crow = cmb + ((size_t)(b*NN + nq))*NN;

  float m_run = NEGINF, l_run = 0.f;
  const f32x4 fz = {0.f, 0.f, 0.f, 0.f};
  f32x4 oacc[4] = {fz, fz, fz, fz};

  const int sm  = t >> 2;
  const int sc0 = (t & 3) * 16;

  for (int it = 0; it < 32; ++it) {
    const int m0 = it * 64;
    __syncthreads();
    {
      const uint4* src = reinterpret_cast<const uint4*>(K + ((size_t)bh*NN + m0 + sm)*64 + sc0);
      uint4 k0v = src[0], k1v = src[1];
      const int s0 = sc0 >> 3;
      *reinterpret_cast<uint4*>(&Ks[sm*64 + (((s0    ) ^ (sm & 7)) << 3)]) = k0v;
      *reinterpret_cast<uint4*>(&Ks[sm*64 + (((s0 + 1) ^ (sm & 7)) << 3)]) = k1v;
    }
    {
      const uint4* src = reinterpret_cast<const uint4*>(V + ((size_t)bh*NN + m0 + sm)*64 + sc0);
      uint4 v0v = src[0], v1v = src[1];
      u16 e[16];
      e[0]=v0v.x&0xffff; e[1]=v0v.x>>16; e[2]=v0v.y&0xffff; e[3]=v0v.y>>16;
      e[4]=v0v.z&0xffff; e[5]=v0v.z>>16; e[6]=v0v.w&0xffff; e[7]=v0v.w>>16;
      e[8]=v1v.x&0xffff; e[9]=v1v.x>>16; e[10]=v1v.y&0xffff; e[11]=v1v.y>>16;
      e[12]=v1v.z&0xffff; e[13]=v1v.z>>16; e[14]=v1v.w&0xffff; e[15]=v1v.w>>16;
      #pragma unroll
      for (int i=0;i<16;++i){
        const int c = sc0 + i;
        Vs[c*64 + ((((sm>>3) ^ (c&7)) << 3) | (sm & 7))] = e[i];
      }
    }
    __syncthreads();

    f32x4 sac[4];
    #pragma unroll
    for (int kt = 0; kt < 4; ++kt) {
      const int key = 16*kt + r15;
      const short8 a0 = *reinterpret_cast<const short8*>(&Ks[key*64 + (((g  ) ^ (key&7)) << 3)]);
      const short8 a1 = *reinterpret_cast<const short8*>(&Ks[key*64 + (((g+4) ^ (key&7)) << 3)]);
      f32x4 s = fz;
      s = __builtin_amdgcn_mfma_f32_16x16x32_bf16(a0, bq0, s, 0, 0, 0);
      s = __builtin_amdgcn_mfma_f32_16x16x32_bf16(a1, bq1, s, 0, 0, 0);
      sac[kt] = s;
    }

    float sv[4][4];
    float pmax = NEGINF;
    #pragma unroll
    for (int kt = 0; kt < 4; ++kt) {
      const u32 cw = *reinterpret_cast<const u32*>(crow + m0 + 16*kt + 4*g);
      #pragma unroll
      for (int j = 0; j < 4; ++j) {
        const u32 ci = (cw >> (8*j)) & 0xffu;
        float x = sac[kt][j] * 0.125f;
        x += (ci & 1) ? 0.f : rw0;
        x += (ci & 2) ? 0.f : rw1;
        x += (ci & 4) ? 0.f : rw2;
        sv[kt][j] = (ci & 8) ? NEGINF : x;
        pmax = fmaxf(pmax, sv[kt][j]);
      }
    }
    float tmax = pmax;
    tmax = fmaxf(tmax, __shfl_xor(tmax, 16));
    tmax = fmaxf(tmax, __shfl_xor(tmax, 32));

    const float nm = fmaxf(m_run, tmax);
    float sc;
    if (nm == NEGINF) { sc = 1.f; }
    else { sc = __expf(m_run - nm); m_run = nm; }

    float psum = 0.f;
    #pragma unroll
    for (int kt = 0; kt < 4; ++kt) {
      float p[4];
      #pragma unroll
      for (int j = 0; j < 4; ++j) {
        p[j] = (nm == NEGINF) ? 0.f : __expf(sv[kt][j] - nm);
        psum += p[j];
      }
      const int slot = 2*kt + (g >> 1);
      const int off  = 4 * (g & 1);
      *reinterpret_cast<ushort4*>(&Ps[w][r15*64 + ((slot ^ (r15 & 7)) << 3) + off]) =
        make_ushort4(f2bf(p[0]), f2bf(p[1]), f2bf(p[2]), f2bf(p[3]));
    }
    psum += __shfl_xor(psum, 16);
    psum += __shfl_xor(psum, 32);
    l_run = l_run * sc + psum;
    #pragma unroll
    for (int ct = 0; ct < 4; ++ct) oacc[ct] *= sc;

    __syncthreads();

    const short8 bp0 = *reinterpret_cast<const short8*>(&Ps[w][r15*64 + (((g  ) ^ (r15 & 7)) << 3)]);
    const short8 bp1 = *reinterpret_cast<const short8*>(&Ps[w][r15*64 + (((g+4) ^ (r15 & 7)) << 3)]);
    #pragma unroll
    for (int ct = 0; ct < 4; ++ct) {
      const int c = 16*ct + r15;
      const short8 av0 = *reinterpret_cast<const short8*>(&Vs[c*64 + (((g  ) ^ (c&7)) << 3)]);
      const short8 av1 = *reinterpret_cast<const short8*>(&Vs[c*64 + (((g+4) ^ (c&7)) << 3)]);
      oacc[ct] = __builtin_amdgcn_mfma_f32_16x16x32_bf16(av0, bp0, oacc[ct], 0, 0, 0);
      oacc[ct] = __builtin_amdgcn_mfma_f32_16x16x32_bf16(av1, bp1, oacc[ct], 0, 0, 0);
    }
  }

  const float rinv = 1.f / l_run;
  #pragma unroll
  for (int ct = 0; ct < 4; ++ct) {
    u16* dst = O + ((size_t)(nq*2 + b))*512 + h*64 + 16*ct + 4*g;
    *reinterpret_cast<ushort4*>(dst) =
      make_ushort4(f2bf(oacc[ct][0]*rinv), f2bf(oacc[ct][1]*rinv),
                   f2bf(oacc[ct][2]*rinv), f2bf(oacc[ct][3]*rinv));
  }
}

extern "C" void kernel_launch(void* const* d_in, const int* in_sizes, int n_in,
                              void* d_out, int out_size, void* d_ws, size_t ws_size,
                              hipStream_t stream)
{
  const float* xq = (const float*)d_in[0];
  const float* xk = (const float*)d_in[1];
  const float* xv = (const float*)d_in[2];
  const int*   am = (const int*)d_in[3];
  const int*   kp = (const int*)d_in[4];
  const float* Wq = (const float*)d_in[5];
  const float* bq = (const float*)d_in[6];
  const float* Wk = (const float*)d_in[7];
  const float* bk = (const float*)d_in[8];
  const float* Wv = (const float*)d_in[9];
  const float* bv = (const float*)d_in[10];
  const float* Wo = (const float*)d_in[11];
  const float* bo = (const float*)d_in[12];
  const float* mw = (const float*)d_in[13];

  u16* Qb = (u16*)d_ws;                       // [16][2048][64] bf16, 4 MB
  u16* Kb = Qb + (size_t)16*NN*64;
  u16* Vb = Kb + (size_t)16*NN*64;
  u16* Ob = Vb + (size_t)16*NN*64;            // [4096][512] bf16, 4 MB
  u8*  cmb = (u8*)(Ob + (size_t)4096*512);    // [2][2048][2048] bytes, 8 MB

  prep_k<<<(2*NN*NN/4 + 255)/256, 256, 0, stream>>>(am, kp, cmb);

  dim3 gg(64, 4);
  gemm_mfma<true , false, false><<<gg, 256, 0, stream>>>(xq, Wq, bq, Qb);
  gemm_mfma<true , false, false><<<gg, 256, 0, stream>>>(xk, Wk, bk, Kb);
  gemm_mfma<true , false, false><<<gg, 256, 0, stream>>>(xv, Wv, bv, Vb);
  attn_mfma<<<dim3(32, 16), 256, 0, stream>>>(Qb, Kb, Vb, cmb, mw, Ob);
  gemm_mfma<false, true , true ><<<gg, 256, 0, stream>>>(Ob, Wo, bo, d_out);
}